// Round 1
// baseline (2383.980 us; speedup 1.0000x reference)
//
#include <hip/hip_runtime.h>
#include <hip/hip_bf16.h>
#include <math.h>

#define D_MODEL 3072
#define N_HEADS 24
#define DH 128
#define L_TXT 256
#define L_IMG 1024
#define L_ALL 1280
#define N_QKV 9216
#define N_MLP 12288
#define MOD_N 18432

typedef __attribute__((ext_vector_type(4))) float f32x4;
typedef __attribute__((ext_vector_type(8))) short bf16x8;

static __device__ __forceinline__ unsigned short f2bf(float f) {
  union { float f; unsigned u; } v; v.f = f;
  unsigned r = v.u + 0x7FFFu + ((v.u >> 16) & 1u);
  return (unsigned short)(r >> 16);
}
static __device__ __forceinline__ unsigned pack2(float a, float b) {
  return (unsigned)f2bf(a) | ((unsigned)f2bf(b) << 16);
}

// ---------------------------------------------------------------- small ops
__global__ void silu_kernel(const float* __restrict__ vec, float* __restrict__ s) {
  int i = blockIdx.x * 256 + threadIdx.x;
  if (i < D_MODEL) { float x = vec[i]; s[i] = x / (1.f + expf(-x)); }
}

__global__ __launch_bounds__(256) void mod_gemv_partial(
    const float* __restrict__ s, const float* __restrict__ w_img,
    const float* __restrict__ w_txt, float* __restrict__ part) {
  int col = blockIdx.x * 256 + threadIdx.x;
  int kb = blockIdx.y;
  const float* w = (blockIdx.z == 0) ? w_img : w_txt;
  float acc = 0.f;
  int k0 = kb * 192;
  #pragma unroll 4
  for (int j = 0; j < 192; ++j)
    acc = fmaf(s[k0 + j], w[(k0 + j) * MOD_N + col], acc);
  part[(blockIdx.z * 16 + kb) * MOD_N + col] = acc;
}

__global__ void mod_reduce(const float* __restrict__ part,
                           const float* __restrict__ b_img,
                           const float* __restrict__ b_txt,
                           float* __restrict__ modv) {
  int i = blockIdx.x * 256 + threadIdx.x;
  int st = i / MOD_N, col = i - st * MOD_N;
  float a = (st == 0) ? b_img[col] : b_txt[col];
  #pragma unroll
  for (int p = 0; p < 16; ++p) a += part[(st * 16 + p) * MOD_N + col];
  modv[i] = a;
}

// LN over D=3072 then (1+scale)*ln + shift, write bf16
__global__ __launch_bounds__(256) void ln_mod_kernel(
    const float* __restrict__ x, unsigned short* __restrict__ xm,
    const float* __restrict__ modv, int sh_off, int sc_off) {
  int row = blockIdx.x, t = threadIdx.x;
  int lane = t & 63, wid = t >> 6;
  const float4* xr = (const float4*)(x + (size_t)row * D_MODEL);
  float4 a = xr[t], b = xr[t + 256], c = xr[t + 512];
  float s = a.x + a.y + a.z + a.w + b.x + b.y + b.z + b.w + c.x + c.y + c.z + c.w;
  float q = a.x * a.x + a.y * a.y + a.z * a.z + a.w * a.w
          + b.x * b.x + b.y * b.y + b.z * b.z + b.w * b.w
          + c.x * c.x + c.y * c.y + c.z * c.z + c.w * c.w;
  #pragma unroll
  for (int m = 1; m < 64; m <<= 1) { s += __shfl_xor(s, m); q += __shfl_xor(q, m); }
  __shared__ float red[8];
  if (lane == 0) { red[wid] = s; red[4 + wid] = q; }
  __syncthreads();
  s = red[0] + red[1] + red[2] + red[3];
  q = red[4] + red[5] + red[6] + red[7];
  float mean = s * (1.f / 3072.f);
  float var = q * (1.f / 3072.f) - mean * mean;
  float inv = 1.f / sqrtf(var + 1e-6f);
  const float4* shp = (const float4*)(modv + sh_off);
  const float4* scp = (const float4*)(modv + sc_off);
  uint2* outp = (uint2*)(xm + (size_t)row * D_MODEL);
  float4 vals[3] = {a, b, c};
  #pragma unroll
  for (int j = 0; j < 3; ++j) {
    float4 sh = shp[t + j * 256], sc = scp[t + j * 256];
    float4 v = vals[j];
    float y0 = (v.x - mean) * inv * (1.f + sc.x) + sh.x;
    float y1 = (v.y - mean) * inv * (1.f + sc.y) + sh.y;
    float y2 = (v.z - mean) * inv * (1.f + sc.z) + sh.z;
    float y3 = (v.w - mean) * inv * (1.f + sc.w) + sh.w;
    uint2 o; o.x = pack2(y0, y1); o.y = pack2(y2, y3);
    outp[t + j * 256] = o;
  }
}

// ---------------------------------------------------------------- GEMM
// C(MxN) = A(bf16, MxK) @ W(f32->bf16, KxN) + bias, epilogues:
// EPI 0: out f32   EPI 1: gelu -> bf16   EPI 2: res + gate*(acc+bias) -> f32
#define LDA_S 40  // LDS A row stride (elems)

static __device__ __forceinline__ void stage_w4(unsigned short* bp, int n0, float4 f) {
  bp[(n0 + 0) * 8] = f2bf(f.x); bp[(n0 + 1) * 8] = f2bf(f.y);
  bp[(n0 + 2) * 8] = f2bf(f.z); bp[(n0 + 3) * 8] = f2bf(f.w);
}

template <int EPI>
__global__ __launch_bounds__(256) void gemm_kernel(
    const unsigned short* __restrict__ A, const float* __restrict__ W,
    const float* __restrict__ bias, float* __restrict__ outF,
    unsigned short* __restrict__ outB, const float* __restrict__ res,
    const float* __restrict__ gate, int M, int N, int K) {
  __shared__ __align__(16) unsigned short As[128 * LDA_S];
  __shared__ __align__(16) unsigned short Bs[4 * 128 * 8]; // [k/8][n][k&7]
  const int tid = threadIdx.x;
  const int lane = tid & 63, wid = tid >> 6;
  const int lm = lane & 15, lk = lane >> 4;
  const int bcol = blockIdx.x * 128, brow = blockIdx.y * 128;
  const int wr = (wid >> 1) * 64, wc = (wid & 1) * 64;
  const int ar = tid >> 1, ac = (tid & 1) * 16;   // A staging: row, col16
  const int wrr = tid >> 3, wc0 = (tid & 7) * 16; // W staging: row, col0

  f32x4 acc[4][4] = {};

  for (int k0 = 0; k0 < K; k0 += 32) {
    const uint4* ag = (const uint4*)(A + (size_t)(brow + ar) * K + k0 + ac);
    uint4 a0 = ag[0], a1 = ag[1];
    const float4* wg = (const float4*)(W + (size_t)(k0 + wrr) * N + bcol + wc0);
    float4 w0 = wg[0], w1 = wg[1], w2 = wg[2], w3 = wg[3];
    __syncthreads();
    *(uint4*)(&As[ar * LDA_S + ac]) = a0;
    *(uint4*)(&As[ar * LDA_S + ac + 8]) = a1;
    {
      unsigned short* bp = &Bs[(wrr >> 3) * 1024 + (wrr & 7)];
      stage_w4(bp, wc0, w0); stage_w4(bp, wc0 + 4, w1);
      stage_w4(bp, wc0 + 8, w2); stage_w4(bp, wc0 + 12, w3);
    }
    __syncthreads();
    bf16x8 af[4], bfr[4];
    #pragma unroll
    for (int mf = 0; mf < 4; ++mf)
      af[mf] = *(const bf16x8*)(&As[(wr + mf * 16 + lm) * LDA_S + lk * 8]);
    #pragma unroll
    for (int nf = 0; nf < 4; ++nf)
      bfr[nf] = *(const bf16x8*)(&Bs[(lk * 128 + wc + nf * 16 + lm) * 8]);
    #pragma unroll
    for (int mf = 0; mf < 4; ++mf)
      #pragma unroll
      for (int nf = 0; nf < 4; ++nf)
        acc[mf][nf] = __builtin_amdgcn_mfma_f32_16x16x32_bf16(af[mf], bfr[nf], acc[mf][nf], 0, 0, 0);
  }

  #pragma unroll
  for (int nf = 0; nf < 4; ++nf) {
    int c = bcol + wc + nf * 16 + lm;
    float bv = bias[c];
    float gv = 0.f;
    if (EPI == 2) gv = gate[c];
    #pragma unroll
    for (int mf = 0; mf < 4; ++mf) {
      int r0 = brow + wr + mf * 16 + lk * 4;
      #pragma unroll
      for (int rg = 0; rg < 4; ++rg) {
        float v = acc[mf][nf][rg] + bv;
        size_t idx = (size_t)(r0 + rg) * N + c;
        if (EPI == 0) {
          outF[idx] = v;
        } else if (EPI == 1) {
          float g = 0.5f * v * (1.f + tanhf(0.7978845608028654f * (v + 0.044715f * v * v * v)));
          outB[idx] = f2bf(g);
        } else {
          outF[idx] = res[idx] + gv * v;
        }
      }
    }
  }
}

// ---------------------------------------------------------------- rms+rope+pack
__global__ __launch_bounds__(256) void rms_rope_kernel(
    const float* __restrict__ qkv_img, const float* __restrict__ qkv_txt,
    const float* __restrict__ img_qn, const float* __restrict__ img_kn,
    const float* __restrict__ txt_qn, const float* __restrict__ txt_kn,
    const float* __restrict__ pe, unsigned short* __restrict__ qa,
    unsigned short* __restrict__ ka, unsigned short* __restrict__ va) {
  int l = blockIdx.x * 4 + (threadIdx.x >> 6);
  int h = blockIdx.y;
  int t = threadIdx.x & 63;
  const float* base; const float* qn; const float* kn;
  if (l < L_TXT) { base = qkv_txt + (size_t)l * N_QKV; qn = txt_qn; kn = txt_kn; }
  else { base = qkv_img + (size_t)(l - L_TXT) * N_QKV; qn = img_qn; kn = img_kn; }
  int d0 = 2 * t;
  float q0 = base[h * DH + d0], q1 = base[h * DH + d0 + 1];
  float k0 = base[D_MODEL + h * DH + d0], k1 = base[D_MODEL + h * DH + d0 + 1];
  float v0 = base[2 * D_MODEL + h * DH + d0], v1 = base[2 * D_MODEL + h * DH + d0 + 1];
  float sq = q0 * q0 + q1 * q1, sk = k0 * k0 + k1 * k1;
  #pragma unroll
  for (int m = 1; m < 64; m <<= 1) { sq += __shfl_xor(sq, m); sk += __shfl_xor(sk, m); }
  float rq = 1.f / sqrtf(sq * (1.f / 128.f) + 1e-6f);
  float rk = 1.f / sqrtf(sk * (1.f / 128.f) + 1e-6f);
  q0 *= rq * qn[d0]; q1 *= rq * qn[d0 + 1];
  k0 *= rk * kn[d0]; k1 *= rk * kn[d0 + 1];
  const float* p = pe + ((size_t)l * 64 + t) * 4;
  float p00 = p[0], p01 = p[1], p10 = p[2], p11 = p[3];
  const float sc = 0.08838834764831845f; // 1/sqrt(128), folded into q
  float Q0 = (p00 * q0 + p01 * q1) * sc;
  float Q1 = (p10 * q0 + p11 * q1) * sc;
  float K0 = p00 * k0 + p01 * k1;
  float K1 = p10 * k0 + p11 * k1;
  size_t o = ((size_t)h * L_ALL + l) * 64 + t;
  ((unsigned*)qa)[o] = pack2(Q0, Q1);
  ((unsigned*)ka)[o] = pack2(K0, K1);
  ((unsigned*)va)[o] = pack2(v0, v1);
}

// ---------------------------------------------------------------- attention
static __device__ __forceinline__ void stage_v8(unsigned short* vp, int n0, uint4 v) {
  vp[(n0 + 0) * 8] = (unsigned short)v.x; vp[(n0 + 1) * 8] = (unsigned short)(v.x >> 16);
  vp[(n0 + 2) * 8] = (unsigned short)v.y; vp[(n0 + 3) * 8] = (unsigned short)(v.y >> 16);
  vp[(n0 + 4) * 8] = (unsigned short)v.z; vp[(n0 + 5) * 8] = (unsigned short)(v.z >> 16);
  vp[(n0 + 6) * 8] = (unsigned short)v.w; vp[(n0 + 7) * 8] = (unsigned short)(v.w >> 16);
}

__global__ __launch_bounds__(256) void attn_kernel(
    const unsigned short* __restrict__ qa, const unsigned short* __restrict__ ka,
    const unsigned short* __restrict__ va, unsigned short* __restrict__ out) {
  __shared__ __align__(16) unsigned short Ks[64 * 136];
  __shared__ __align__(16) unsigned short Vs[16 * 128 * 8]; // [kv/8][d][kv&7]
  __shared__ __align__(16) unsigned short Ps[4][16 * 72];
  int h = blockIdx.y, qt = blockIdx.x;
  int tid = threadIdx.x, lane = tid & 63, wid = tid >> 6;
  int lm = lane & 15, lk = lane >> 4;
  const unsigned short* qh = qa + (size_t)h * L_ALL * DH;
  const unsigned short* kh = ka + (size_t)h * L_ALL * DH;
  const unsigned short* vh = va + (size_t)h * L_ALL * DH;

  int qrow = qt * 64 + wid * 16 + lm;
  bf16x8 qf[4];
  #pragma unroll
  for (int kk = 0; kk < 4; ++kk)
    qf[kk] = *(const bf16x8*)(qh + (size_t)qrow * DH + kk * 32 + lk * 8);

  float m_run[4] = {-INFINITY, -INFINITY, -INFINITY, -INFINITY};
  float s_run[4] = {0.f, 0.f, 0.f, 0.f};
  f32x4 o[8] = {};

  int sr = tid >> 2, sc = (tid & 3) * 32; // staging: row, col0 (elems)

  for (int kt = 0; kt < L_ALL / 64; ++kt) {
    const uint4* kg = (const uint4*)(kh + (size_t)(kt * 64 + sr) * DH + sc);
    uint4 kv0 = kg[0], kv1 = kg[1], kv2 = kg[2], kv3 = kg[3];
    const uint4* vg = (const uint4*)(vh + (size_t)(kt * 64 + sr) * DH + sc);
    uint4 vv0 = vg[0], vv1 = vg[1], vv2 = vg[2], vv3 = vg[3];
    __syncthreads();
    uint4* kd = (uint4*)(&Ks[sr * 136 + sc]);
    kd[0] = kv0; kd[1] = kv1; kd[2] = kv2; kd[3] = kv3;
    {
      unsigned short* vp = &Vs[(sr >> 3) * 1024 + (sr & 7)];
      stage_v8(vp, sc, vv0); stage_v8(vp, sc + 8, vv1);
      stage_v8(vp, sc + 16, vv2); stage_v8(vp, sc + 24, vv3);
    }
    __syncthreads();

    f32x4 S[4] = {};
    #pragma unroll
    for (int kk = 0; kk < 4; ++kk)
      #pragma unroll
      for (int nf = 0; nf < 4; ++nf) {
        bf16x8 bv = *(const bf16x8*)(&Ks[(nf * 16 + lm) * 136 + kk * 32 + lk * 8]);
        S[nf] = __builtin_amdgcn_mfma_f32_16x16x32_bf16(qf[kk], bv, S[nf], 0, 0, 0);
      }

    float corr[4];
    #pragma unroll
    for (int r = 0; r < 4; ++r) {
      float mx = fmaxf(fmaxf(S[0][r], S[1][r]), fmaxf(S[2][r], S[3][r]));
      mx = fmaxf(mx, __shfl_xor(mx, 1));
      mx = fmaxf(mx, __shfl_xor(mx, 2));
      mx = fmaxf(mx, __shfl_xor(mx, 4));
      mx = fmaxf(mx, __shfl_xor(mx, 8));
      float mn = fmaxf(m_run[r], mx);
      corr[r] = expf(m_run[r] - mn);
      m_run[r] = mn;
    }
    float rs[4] = {0.f, 0.f, 0.f, 0.f};
    float pv[4][4];
    #pragma unroll
    for (int nf = 0; nf < 4; ++nf)
      #pragma unroll
      for (int r = 0; r < 4; ++r) {
        pv[nf][r] = expf(S[nf][r] - m_run[r]);
        rs[r] += pv[nf][r];
      }
    #pragma unroll
    for (int nf = 0; nf < 4; ++nf)
      #pragma unroll
      for (int r = 0; r < 4; ++r)
        Ps[wid][(lk * 4 + r) * 72 + nf * 16 + lm] = f2bf(pv[nf][r]);
    #pragma unroll
    for (int r = 0; r < 4; ++r) {
      rs[r] += __shfl_xor(rs[r], 1);
      rs[r] += __shfl_xor(rs[r], 2);
      rs[r] += __shfl_xor(rs[r], 4);
      rs[r] += __shfl_xor(rs[r], 8);
      s_run[r] = s_run[r] * corr[r] + rs[r];
    }
    #pragma unroll
    for (int nf = 0; nf < 8; ++nf)
      #pragma unroll
      for (int r = 0; r < 4; ++r)
        o[nf][r] *= corr[r];

    #pragma unroll
    for (int kk2 = 0; kk2 < 2; ++kk2) {
      bf16x8 pa = *(const bf16x8*)(&Ps[wid][lm * 72 + kk2 * 32 + lk * 8]);
      #pragma unroll
      for (int nf = 0; nf < 8; ++nf) {
        bf16x8 vb = *(const bf16x8*)(&Vs[((kk2 * 4 + lk) * 128 + nf * 16 + lm) * 8]);
        o[nf] = __builtin_amdgcn_mfma_f32_16x16x32_bf16(pa, vb, o[nf], 0, 0, 0);
      }
    }
  }

  float inv[4];
  #pragma unroll
  for (int r = 0; r < 4; ++r) inv[r] = 1.f / s_run[r];
  #pragma unroll
  for (int nf = 0; nf < 8; ++nf)
    #pragma unroll
    for (int r = 0; r < 4; ++r) {
      int row = qt * 64 + wid * 16 + lk * 4 + r;
      int col = h * DH + nf * 16 + lm;
      out[(size_t)row * D_MODEL + col] = f2bf(o[nf][r] * inv[r]);
    }
}

// ---------------------------------------------------------------- launch
extern "C" void kernel_launch(void* const* d_in, const int* in_sizes, int n_in,
                              void* d_out, int out_size, void* d_ws, size_t ws_size,
                              hipStream_t stream) {
  const float* img = (const float*)d_in[0];
  const float* txt = (const float*)d_in[1];
  const float* vec = (const float*)d_in[2];
  const float* pe = (const float*)d_in[3];
  const float* img_mod_w = (const float*)d_in[4];
  const float* img_mod_b = (const float*)d_in[5];
  const float* img_qkv_w = (const float*)d_in[6];
  const float* img_qkv_b = (const float*)d_in[7];
  const float* img_qnorm = (const float*)d_in[8];
  const float* img_knorm = (const float*)d_in[9];
  const float* img_proj_w = (const float*)d_in[10];
  const float* img_proj_b = (const float*)d_in[11];
  const float* img_mlp_w1 = (const float*)d_in[12];
  const float* img_mlp_b1 = (const float*)d_in[13];
  const float* img_mlp_w2 = (const float*)d_in[14];
  const float* img_mlp_b2 = (const float*)d_in[15];
  const float* txt_mod_w = (const float*)d_in[16];
  const float* txt_mod_b = (const float*)d_in[17];
  const float* txt_qkv_w = (const float*)d_in[18];
  const float* txt_qkv_b = (const float*)d_in[19];
  const float* txt_qnorm = (const float*)d_in[20];
  const float* txt_knorm = (const float*)d_in[21];
  const float* txt_proj_w = (const float*)d_in[22];
  const float* txt_proj_b = (const float*)d_in[23];
  const float* txt_mlp_w1 = (const float*)d_in[24];
  const float* txt_mlp_b1 = (const float*)d_in[25];
  const float* txt_mlp_w2 = (const float*)d_in[26];
  const float* txt_mlp_b2 = (const float*)d_in[27];

  char* wsb = (char*)d_ws;
  // ws layout (bytes), peak ~81.2 MB with region reuse:
  float* silu_s = (float*)(wsb + 0);                    // 3072 f
  float* part = (float*)(wsb + 16384);                  // 2*16*18432 f
  float* modv = (float*)(wsb + 2375680);                // 2*18432 f
  unsigned short* xm_img = (unsigned short*)(wsb + 2523136); // 7.86 MB (xm, later attn)
  unsigned short* xm_txt = xm_img + (size_t)L_IMG * D_MODEL;
  float* qkv_img = (float*)(wsb + 10387456);            // 47.2 MB (qkv, later x2+h)
  float* qkv_txt = qkv_img + (size_t)L_IMG * N_QKV;
  unsigned short* qa = (unsigned short*)(wsb + 57573376);
  unsigned short* ka = (unsigned short*)(wsb + 65437696);
  unsigned short* va = (unsigned short*)(wsb + 73302016); // ends 81,166,336
  unsigned short* attn = xm_img;                        // reuse (xm dead)
  float* img2 = (float*)(wsb + 10387456);               // reuse (qkv dead)
  float* txt2 = img2 + (size_t)L_IMG * D_MODEL;
  unsigned short* xm2_img = qa;                         // reuse (qa dead)
  unsigned short* xm2_txt = xm2_img + (size_t)L_IMG * D_MODEL;
  unsigned short* h_img = (unsigned short*)(wsb + 10387456 + 15728640);
  unsigned short* h_txt = h_img + (size_t)L_IMG * N_MLP;
  float* out_img = (float*)d_out;
  float* out_txt = out_img + (size_t)L_IMG * D_MODEL;
  float* mod_img = modv;
  float* mod_txt = modv + MOD_N;

  silu_kernel<<<12, 256, 0, stream>>>(vec, silu_s);
  mod_gemv_partial<<<dim3(72, 16, 2), 256, 0, stream>>>(silu_s, img_mod_w, txt_mod_w, part);
  mod_reduce<<<144, 256, 0, stream>>>(part, img_mod_b, txt_mod_b, modv);
  ln_mod_kernel<<<L_IMG, 256, 0, stream>>>(img, xm_img, mod_img, 0, 3072);
  ln_mod_kernel<<<L_TXT, 256, 0, stream>>>(txt, xm_txt, mod_txt, 0, 3072);
  gemm_kernel<0><<<dim3(72, 8), 256, 0, stream>>>(xm_img, img_qkv_w, img_qkv_b, qkv_img, nullptr, nullptr, nullptr, L_IMG, N_QKV, D_MODEL);
  gemm_kernel<0><<<dim3(72, 2), 256, 0, stream>>>(xm_txt, txt_qkv_w, txt_qkv_b, qkv_txt, nullptr, nullptr, nullptr, L_TXT, N_QKV, D_MODEL);
  rms_rope_kernel<<<dim3(L_ALL / 4, N_HEADS), 256, 0, stream>>>(qkv_img, qkv_txt, img_qnorm, img_knorm, txt_qnorm, txt_knorm, pe, qa, ka, va);
  attn_kernel<<<dim3(L_ALL / 64, N_HEADS), 256, 0, stream>>>(qa, ka, va, attn);
  gemm_kernel<2><<<dim3(24, 8), 256, 0, stream>>>(attn + (size_t)L_TXT * D_MODEL, img_proj_w, img_proj_b, img2, nullptr, img, mod_img + 6144, L_IMG, D_MODEL, D_MODEL);
  gemm_kernel<2><<<dim3(24, 2), 256, 0, stream>>>(attn, txt_proj_w, txt_proj_b, txt2, nullptr, txt, mod_txt + 6144, L_TXT, D_MODEL, D_MODEL);
  ln_mod_kernel<<<L_IMG, 256, 0, stream>>>(img2, xm2_img, mod_img, 9216, 12288);
  ln_mod_kernel<<<L_TXT, 256, 0, stream>>>(txt2, xm2_txt, mod_txt, 9216, 12288);
  gemm_kernel<1><<<dim3(96, 8), 256, 0, stream>>>(xm2_img, img_mlp_w1, img_mlp_b1, nullptr, h_img, nullptr, nullptr, L_IMG, N_MLP, D_MODEL);
  gemm_kernel<1><<<dim3(96, 2), 256, 0, stream>>>(xm2_txt, txt_mlp_w1, txt_mlp_b1, nullptr, h_txt, nullptr, nullptr, L_TXT, N_MLP, D_MODEL);
  gemm_kernel<2><<<dim3(24, 8), 256, 0, stream>>>(h_img, img_mlp_w2, img_mlp_b2, out_img, nullptr, img2, mod_img + 15360, L_IMG, D_MODEL, N_MLP);
  gemm_kernel<2><<<dim3(24, 2), 256, 0, stream>>>(h_txt, txt_mlp_w2, txt_mlp_b2, out_txt, nullptr, txt2, mod_txt + 15360, L_TXT, D_MODEL, N_MLP);
}

// Round 2
// 1123.707 us; speedup vs baseline: 2.1215x; 2.1215x over previous
//
#include <hip/hip_runtime.h>
#include <hip/hip_bf16.h>
#include <math.h>

#define D_MODEL 3072
#define N_HEADS 24
#define DH 128
#define L_TXT 256
#define L_IMG 1024
#define L_ALL 1280
#define N_QKV 9216
#define N_MLP 12288
#define MOD_N 18432

typedef __attribute__((ext_vector_type(4))) float f32x4;
typedef __attribute__((ext_vector_type(8))) short bf16x8;

static __device__ __forceinline__ unsigned short f2bf(float f) {
  __hip_bfloat16 h = __float2bfloat16(f);
  union { __hip_bfloat16 h; unsigned short u; } v; v.h = h;
  return v.u;
}
static __device__ __forceinline__ unsigned pack2(float a, float b) {
  return (unsigned)f2bf(a) | ((unsigned)f2bf(b) << 16);
}

// ---------------------------------------------------------------- small ops
__global__ void silu_kernel(const float* __restrict__ vec, float* __restrict__ s) {
  int i = blockIdx.x * 256 + threadIdx.x;
  if (i < D_MODEL) { float x = vec[i]; s[i] = x / (1.f + expf(-x)); }
}

__global__ __launch_bounds__(256) void mod_gemv_partial(
    const float* __restrict__ s, const float* __restrict__ w_img,
    const float* __restrict__ w_txt, float* __restrict__ part) {
  int col = blockIdx.x * 256 + threadIdx.x;
  int kb = blockIdx.y;
  const float* w = (blockIdx.z == 0) ? w_img : w_txt;
  float acc = 0.f;
  int k0 = kb * 192;
  #pragma unroll 8
  for (int j = 0; j < 192; ++j)
    acc = fmaf(s[k0 + j], w[(k0 + j) * MOD_N + col], acc);
  part[(blockIdx.z * 16 + kb) * MOD_N + col] = acc;
}

__global__ void mod_reduce(const float* __restrict__ part,
                           const float* __restrict__ b_img,
                           const float* __restrict__ b_txt,
                           float* __restrict__ modv) {
  int i = blockIdx.x * 256 + threadIdx.x;
  int st = i / MOD_N, col = i - st * MOD_N;
  float a = (st == 0) ? b_img[col] : b_txt[col];
  #pragma unroll
  for (int p = 0; p < 16; ++p) a += part[(st * 16 + p) * MOD_N + col];
  modv[i] = a;
}

// LN over D=3072 then (1+scale)*ln + shift, write bf16
__global__ __launch_bounds__(256) void ln_mod_kernel(
    const float* __restrict__ x, unsigned short* __restrict__ xm,
    const float* __restrict__ modv, int sh_off, int sc_off) {
  int row = blockIdx.x, t = threadIdx.x;
  int lane = t & 63, wid = t >> 6;
  const float4* xr = (const float4*)(x + (size_t)row * D_MODEL);
  float4 a = xr[t], b = xr[t + 256], c = xr[t + 512];
  float s = a.x + a.y + a.z + a.w + b.x + b.y + b.z + b.w + c.x + c.y + c.z + c.w;
  float q = a.x * a.x + a.y * a.y + a.z * a.z + a.w * a.w
          + b.x * b.x + b.y * b.y + b.z * b.z + b.w * b.w
          + c.x * c.x + c.y * c.y + c.z * c.z + c.w * c.w;
  #pragma unroll
  for (int m = 1; m < 64; m <<= 1) { s += __shfl_xor(s, m); q += __shfl_xor(q, m); }
  __shared__ float red[8];
  if (lane == 0) { red[wid] = s; red[4 + wid] = q; }
  __syncthreads();
  s = red[0] + red[1] + red[2] + red[3];
  q = red[4] + red[5] + red[6] + red[7];
  float mean = s * (1.f / 3072.f);
  float var = q * (1.f / 3072.f) - mean * mean;
  float inv = 1.f / sqrtf(var + 1e-6f);
  const float4* shp = (const float4*)(modv + sh_off);
  const float4* scp = (const float4*)(modv + sc_off);
  uint2* outp = (uint2*)(xm + (size_t)row * D_MODEL);
  float4 vals[3] = {a, b, c};
  #pragma unroll
  for (int j = 0; j < 3; ++j) {
    float4 sh = shp[t + j * 256], sc = scp[t + j * 256];
    float4 v = vals[j];
    float y0 = (v.x - mean) * inv * (1.f + sc.x) + sh.x;
    float y1 = (v.y - mean) * inv * (1.f + sc.y) + sh.y;
    float y2 = (v.z - mean) * inv * (1.f + sc.z) + sh.z;
    float y3 = (v.w - mean) * inv * (1.f + sc.w) + sh.w;
    uint2 o; o.x = pack2(y0, y1); o.y = pack2(y2, y3);
    outp[t + j * 256] = o;
  }
}

// ---------------------------------------------------------------- GEMM v2
// Double-buffered, software-pipelined. Handles both streams (img+txt) in one
// dispatch via a linearized tile id. C(MxN) = A(bf16,MxK) @ W(f32->bf16,KxN).
// EPI 0: out f32   EPI 1: gelu -> bf16   EPI 2: res + gate*(acc+bias) -> f32
#define LDA_S 40   // LDS A row stride (elems)
#define AS_ELE (128 * LDA_S)
#define BS_ELE 4096  // 4 kgroups * 128 n * 8

// B LDS layout: [k/8][n][k&7] with XOR swizzle on elem idx: e ^= ((n>>4)&3)<<3
static __device__ __forceinline__ int bidx(int kg, int n, int kq) {
  int e = kg * 1024 + n * 8 + kq;
  return e ^ (((n >> 4) & 3) << 3);
}

template <int EPI>
__global__ __launch_bounds__(256) void gemm2_kernel(
    const unsigned short* __restrict__ A0, const float* __restrict__ W0,
    const float* __restrict__ bias0, float* __restrict__ outF0,
    unsigned short* __restrict__ outB0, const float* __restrict__ res0,
    const float* __restrict__ gate0,
    const unsigned short* __restrict__ A1, const float* __restrict__ W1,
    const float* __restrict__ bias1, float* __restrict__ outF1,
    unsigned short* __restrict__ outB1, const float* __restrict__ res1,
    const float* __restrict__ gate1,
    int tiles0, int N, int K) {
  __shared__ __align__(16) unsigned short As[2 * AS_ELE];
  __shared__ __align__(16) unsigned short Bs[2 * BS_ELE];

  const int nx = N >> 7;
  int b = blockIdx.x;
  const unsigned short* A; const float* W; const float* bias;
  float* outF; unsigned short* outB; const float* res; const float* gate;
  if (b < tiles0) {
    A = A0; W = W0; bias = bias0; outF = outF0; outB = outB0; res = res0; gate = gate0;
  } else {
    b -= tiles0;
    A = A1; W = W1; bias = bias1; outF = outF1; outB = outB1; res = res1; gate = gate1;
  }
  const int by = b / nx;
  const int bx = b - by * nx;
  const int bcol = bx * 128, brow = by * 128;

  const int tid = threadIdx.x;
  const int lane = tid & 63, wid = tid >> 6;
  const int lm = lane & 15, lk = lane >> 4;
  const int wr = (wid >> 1) * 64, wc = (wid & 1) * 64;
  const int ar = tid >> 1, ac = (tid & 1) * 16;   // A staging: row, col16
  const int wrr = tid >> 3, wc0 = (tid & 7) * 16; // W staging: row, col0

  const unsigned short* Ap = A + (size_t)(brow + ar) * K + ac;
  const float* Wp = W + (size_t)wrr * N + bcol + wc0;
  const size_t wstep = (size_t)32 * N;

  f32x4 acc[4][4] = {};
  uint4 a0, a1;
  float4 w0, w1, w2, w3;

  // prologue: issue loads for tile 0
  {
    const uint4* ag = (const uint4*)Ap;
    a0 = ag[0]; a1 = ag[1];
    const float4* wg = (const float4*)Wp;
    w0 = wg[0]; w1 = wg[1]; w2 = wg[2]; w3 = wg[3];
  }

  const int nt = K >> 5;
  int cur = 0;
  for (int t = 0; t < nt; ++t) {
    unsigned short* Asb = As + cur * AS_ELE;
    unsigned short* Bsb = Bs + cur * BS_ELE;
    // stage regs -> LDS (waits vmcnt internally)
    *(uint4*)(&Asb[ar * LDA_S + ac]) = a0;
    *(uint4*)(&Asb[ar * LDA_S + ac + 8]) = a1;
    {
      int kg = wrr >> 3, kq = wrr & 7;
      Bsb[bidx(kg, wc0 + 0, kq)] = f2bf(w0.x);  Bsb[bidx(kg, wc0 + 1, kq)] = f2bf(w0.y);
      Bsb[bidx(kg, wc0 + 2, kq)] = f2bf(w0.z);  Bsb[bidx(kg, wc0 + 3, kq)] = f2bf(w0.w);
      Bsb[bidx(kg, wc0 + 4, kq)] = f2bf(w1.x);  Bsb[bidx(kg, wc0 + 5, kq)] = f2bf(w1.y);
      Bsb[bidx(kg, wc0 + 6, kq)] = f2bf(w1.z);  Bsb[bidx(kg, wc0 + 7, kq)] = f2bf(w1.w);
      Bsb[bidx(kg, wc0 + 8, kq)] = f2bf(w2.x);  Bsb[bidx(kg, wc0 + 9, kq)] = f2bf(w2.y);
      Bsb[bidx(kg, wc0 + 10, kq)] = f2bf(w2.z); Bsb[bidx(kg, wc0 + 11, kq)] = f2bf(w2.w);
      Bsb[bidx(kg, wc0 + 12, kq)] = f2bf(w3.x); Bsb[bidx(kg, wc0 + 13, kq)] = f2bf(w3.y);
      Bsb[bidx(kg, wc0 + 14, kq)] = f2bf(w3.z); Bsb[bidx(kg, wc0 + 15, kq)] = f2bf(w3.w);
    }
    __syncthreads();
    // issue loads for tile t+1 (stay in flight during compute)
    if (t + 1 < nt) {
      const uint4* ag = (const uint4*)(Ap + (t + 1) * 32);
      a0 = ag[0]; a1 = ag[1];
      const float4* wg = (const float4*)(Wp + (size_t)(t + 1) * wstep);
      w0 = wg[0]; w1 = wg[1]; w2 = wg[2]; w3 = wg[3];
    }
    // compute from buf cur
    bf16x8 af[4], bfr[4];
    #pragma unroll
    for (int mf = 0; mf < 4; ++mf)
      af[mf] = *(const bf16x8*)(&Asb[(wr + mf * 16 + lm) * LDA_S + lk * 8]);
    #pragma unroll
    for (int nf = 0; nf < 4; ++nf) {
      int n = wc + nf * 16 + lm;
      int e = (lk * 1024 + n * 8) ^ ((((n >> 4)) & 3) << 3);
      bfr[nf] = *(const bf16x8*)(&Bsb[e]);
    }
    #pragma unroll
    for (int mf = 0; mf < 4; ++mf)
      #pragma unroll
      for (int nf = 0; nf < 4; ++nf)
        acc[mf][nf] = __builtin_amdgcn_mfma_f32_16x16x32_bf16(af[mf], bfr[nf], acc[mf][nf], 0, 0, 0);
    __syncthreads();
    cur ^= 1;
  }

  #pragma unroll
  for (int nf = 0; nf < 4; ++nf) {
    int c = bcol + wc + nf * 16 + lm;
    float bv = bias[c];
    float gv = 0.f;
    if (EPI == 2) gv = gate[c];
    #pragma unroll
    for (int mf = 0; mf < 4; ++mf) {
      int r0 = brow + wr + mf * 16 + lk * 4;
      #pragma unroll
      for (int rg = 0; rg < 4; ++rg) {
        float v = acc[mf][nf][rg] + bv;
        size_t idx = (size_t)(r0 + rg) * N + c;
        if (EPI == 0) {
          outF[idx] = v;
        } else if (EPI == 1) {
          float g = 0.5f * v * (1.f + tanhf(0.7978845608028654f * (v + 0.044715f * v * v * v)));
          outB[idx] = f2bf(g);
        } else {
          outF[idx] = res[idx] + gv * v;
        }
      }
    }
  }
}

// ---------------------------------------------------------------- rms+rope+pack
__global__ __launch_bounds__(256) void rms_rope_kernel(
    const float* __restrict__ qkv_img, const float* __restrict__ qkv_txt,
    const float* __restrict__ img_qn, const float* __restrict__ img_kn,
    const float* __restrict__ txt_qn, const float* __restrict__ txt_kn,
    const float* __restrict__ pe, unsigned short* __restrict__ qa,
    unsigned short* __restrict__ ka, unsigned short* __restrict__ va) {
  int l = blockIdx.x * 4 + (threadIdx.x >> 6);
  int h = blockIdx.y;
  int t = threadIdx.x & 63;
  const float* base; const float* qn; const float* kn;
  if (l < L_TXT) { base = qkv_txt + (size_t)l * N_QKV; qn = txt_qn; kn = txt_kn; }
  else { base = qkv_img + (size_t)(l - L_TXT) * N_QKV; qn = img_qn; kn = img_kn; }
  int d0 = 2 * t;
  float q0 = base[h * DH + d0], q1 = base[h * DH + d0 + 1];
  float k0 = base[D_MODEL + h * DH + d0], k1 = base[D_MODEL + h * DH + d0 + 1];
  float v0 = base[2 * D_MODEL + h * DH + d0], v1 = base[2 * D_MODEL + h * DH + d0 + 1];
  float sq = q0 * q0 + q1 * q1, sk = k0 * k0 + k1 * k1;
  #pragma unroll
  for (int m = 1; m < 64; m <<= 1) { sq += __shfl_xor(sq, m); sk += __shfl_xor(sk, m); }
  float rq = 1.f / sqrtf(sq * (1.f / 128.f) + 1e-6f);
  float rk = 1.f / sqrtf(sk * (1.f / 128.f) + 1e-6f);
  q0 *= rq * qn[d0]; q1 *= rq * qn[d0 + 1];
  k0 *= rk * kn[d0]; k1 *= rk * kn[d0 + 1];
  const float* p = pe + ((size_t)l * 64 + t) * 4;
  float p00 = p[0], p01 = p[1], p10 = p[2], p11 = p[3];
  const float sc = 0.08838834764831845f; // 1/sqrt(128), folded into q
  float Q0 = (p00 * q0 + p01 * q1) * sc;
  float Q1 = (p10 * q0 + p11 * q1) * sc;
  float K0 = p00 * k0 + p01 * k1;
  float K1 = p10 * k0 + p11 * k1;
  size_t o = ((size_t)h * L_ALL + l) * 64 + t;
  ((unsigned*)qa)[o] = pack2(Q0, Q1);
  ((unsigned*)ka)[o] = pack2(K0, K1);
  ((unsigned*)va)[o] = pack2(v0, v1);
}

// ---------------------------------------------------------------- attention
static __device__ __forceinline__ void stage_v8(unsigned short* vp, int n0, uint4 v) {
  vp[(n0 + 0) * 8] = (unsigned short)v.x; vp[(n0 + 1) * 8] = (unsigned short)(v.x >> 16);
  vp[(n0 + 2) * 8] = (unsigned short)v.y; vp[(n0 + 3) * 8] = (unsigned short)(v.y >> 16);
  vp[(n0 + 4) * 8] = (unsigned short)v.z; vp[(n0 + 5) * 8] = (unsigned short)(v.z >> 16);
  vp[(n0 + 6) * 8] = (unsigned short)v.w; vp[(n0 + 7) * 8] = (unsigned short)(v.w >> 16);
}

__global__ __launch_bounds__(256) void attn_kernel(
    const unsigned short* __restrict__ qa, const unsigned short* __restrict__ ka,
    const unsigned short* __restrict__ va, unsigned short* __restrict__ out) {
  __shared__ __align__(16) unsigned short Ks[64 * 136];
  __shared__ __align__(16) unsigned short Vs[16 * 128 * 8]; // [kv/8][d][kv&7]
  __shared__ __align__(16) unsigned short Ps[4][16 * 72];
  int h = blockIdx.y, qt = blockIdx.x;
  int tid = threadIdx.x, lane = tid & 63, wid = tid >> 6;
  int lm = lane & 15, lk = lane >> 4;
  const unsigned short* qh = qa + (size_t)h * L_ALL * DH;
  const unsigned short* kh = ka + (size_t)h * L_ALL * DH;
  const unsigned short* vh = va + (size_t)h * L_ALL * DH;

  int qrow = qt * 64 + wid * 16 + lm;
  bf16x8 qf[4];
  #pragma unroll
  for (int kk = 0; kk < 4; ++kk)
    qf[kk] = *(const bf16x8*)(qh + (size_t)qrow * DH + kk * 32 + lk * 8);

  float m_run[4] = {-INFINITY, -INFINITY, -INFINITY, -INFINITY};
  float s_run[4] = {0.f, 0.f, 0.f, 0.f};
  f32x4 o[8] = {};

  int sr = tid >> 2, sc = (tid & 3) * 32; // staging: row, col0 (elems)

  for (int kt = 0; kt < L_ALL / 64; ++kt) {
    const uint4* kg = (const uint4*)(kh + (size_t)(kt * 64 + sr) * DH + sc);
    uint4 kv0 = kg[0], kv1 = kg[1], kv2 = kg[2], kv3 = kg[3];
    const uint4* vg = (const uint4*)(vh + (size_t)(kt * 64 + sr) * DH + sc);
    uint4 vv0 = vg[0], vv1 = vg[1], vv2 = vg[2], vv3 = vg[3];
    __syncthreads();
    uint4* kd = (uint4*)(&Ks[sr * 136 + sc]);
    kd[0] = kv0; kd[1] = kv1; kd[2] = kv2; kd[3] = kv3;
    {
      unsigned short* vp = &Vs[(sr >> 3) * 1024 + (sr & 7)];
      stage_v8(vp, sc, vv0); stage_v8(vp, sc + 8, vv1);
      stage_v8(vp, sc + 16, vv2); stage_v8(vp, sc + 24, vv3);
    }
    __syncthreads();

    f32x4 S[4] = {};
    #pragma unroll
    for (int kk = 0; kk < 4; ++kk)
      #pragma unroll
      for (int nf = 0; nf < 4; ++nf) {
        bf16x8 bv = *(const bf16x8*)(&Ks[(nf * 16 + lm) * 136 + kk * 32 + lk * 8]);
        S[nf] = __builtin_amdgcn_mfma_f32_16x16x32_bf16(qf[kk], bv, S[nf], 0, 0, 0);
      }

    float corr[4];
    #pragma unroll
    for (int r = 0; r < 4; ++r) {
      float mx = fmaxf(fmaxf(S[0][r], S[1][r]), fmaxf(S[2][r], S[3][r]));
      mx = fmaxf(mx, __shfl_xor(mx, 1));
      mx = fmaxf(mx, __shfl_xor(mx, 2));
      mx = fmaxf(mx, __shfl_xor(mx, 4));
      mx = fmaxf(mx, __shfl_xor(mx, 8));
      float mn = fmaxf(m_run[r], mx);
      corr[r] = expf(m_run[r] - mn);
      m_run[r] = mn;
    }
    float rs[4] = {0.f, 0.f, 0.f, 0.f};
    float pv[4][4];
    #pragma unroll
    for (int nf = 0; nf < 4; ++nf)
      #pragma unroll
      for (int r = 0; r < 4; ++r) {
        pv[nf][r] = expf(S[nf][r] - m_run[r]);
        rs[r] += pv[nf][r];
      }
    #pragma unroll
    for (int nf = 0; nf < 4; ++nf)
      #pragma unroll
      for (int r = 0; r < 4; ++r)
        Ps[wid][(lk * 4 + r) * 72 + nf * 16 + lm] = f2bf(pv[nf][r]);
    #pragma unroll
    for (int r = 0; r < 4; ++r) {
      rs[r] += __shfl_xor(rs[r], 1);
      rs[r] += __shfl_xor(rs[r], 2);
      rs[r] += __shfl_xor(rs[r], 4);
      rs[r] += __shfl_xor(rs[r], 8);
      s_run[r] = s_run[r] * corr[r] + rs[r];
    }
    #pragma unroll
    for (int nf = 0; nf < 8; ++nf)
      #pragma unroll
      for (int r = 0; r < 4; ++r)
        o[nf][r] *= corr[r];

    #pragma unroll
    for (int kk2 = 0; kk2 < 2; ++kk2) {
      bf16x8 pa = *(const bf16x8*)(&Ps[wid][lm * 72 + kk2 * 32 + lk * 8]);
      #pragma unroll
      for (int nf = 0; nf < 8; ++nf) {
        bf16x8 vb = *(const bf16x8*)(&Vs[((kk2 * 4 + lk) * 128 + nf * 16 + lm) * 8]);
        o[nf] = __builtin_amdgcn_mfma_f32_16x16x32_bf16(pa, vb, o[nf], 0, 0, 0);
      }
    }
  }

  float inv[4];
  #pragma unroll
  for (int r = 0; r < 4; ++r) inv[r] = 1.f / s_run[r];
  #pragma unroll
  for (int nf = 0; nf < 8; ++nf)
    #pragma unroll
    for (int r = 0; r < 4; ++r) {
      int row = qt * 64 + wid * 16 + lk * 4 + r;
      int col = h * DH + nf * 16 + lm;
      out[(size_t)row * D_MODEL + col] = f2bf(o[nf][r] * inv[r]);
    }
}

// ---------------------------------------------------------------- launch
extern "C" void kernel_launch(void* const* d_in, const int* in_sizes, int n_in,
                              void* d_out, int out_size, void* d_ws, size_t ws_size,
                              hipStream_t stream) {
  const float* img = (const float*)d_in[0];
  const float* txt = (const float*)d_in[1];
  const float* vec = (const float*)d_in[2];
  const float* pe = (const float*)d_in[3];
  const float* img_mod_w = (const float*)d_in[4];
  const float* img_mod_b = (const float*)d_in[5];
  const float* img_qkv_w = (const float*)d_in[6];
  const float* img_qkv_b = (const float*)d_in[7];
  const float* img_qnorm = (const float*)d_in[8];
  const float* img_knorm = (const float*)d_in[9];
  const float* img_proj_w = (const float*)d_in[10];
  const float* img_proj_b = (const float*)d_in[11];
  const float* img_mlp_w1 = (const float*)d_in[12];
  const float* img_mlp_b1 = (const float*)d_in[13];
  const float* img_mlp_w2 = (const float*)d_in[14];
  const float* img_mlp_b2 = (const float*)d_in[15];
  const float* txt_mod_w = (const float*)d_in[16];
  const float* txt_mod_b = (const float*)d_in[17];
  const float* txt_qkv_w = (const float*)d_in[18];
  const float* txt_qkv_b = (const float*)d_in[19];
  const float* txt_qnorm = (const float*)d_in[20];
  const float* txt_knorm = (const float*)d_in[21];
  const float* txt_proj_w = (const float*)d_in[22];
  const float* txt_proj_b = (const float*)d_in[23];
  const float* txt_mlp_w1 = (const float*)d_in[24];
  const float* txt_mlp_b1 = (const float*)d_in[25];
  const float* txt_mlp_w2 = (const float*)d_in[26];
  const float* txt_mlp_b2 = (const float*)d_in[27];

  char* wsb = (char*)d_ws;
  float* silu_s = (float*)(wsb + 0);                    // 3072 f
  float* part = (float*)(wsb + 16384);                  // 2*16*18432 f
  float* modv = (float*)(wsb + 2375680);                // 2*18432 f
  unsigned short* xm_img = (unsigned short*)(wsb + 2523136); // 7.86 MB (xm, later attn)
  unsigned short* xm_txt = xm_img + (size_t)L_IMG * D_MODEL;
  float* qkv_img = (float*)(wsb + 10387456);            // 47.2 MB (qkv, later x2+h)
  float* qkv_txt = qkv_img + (size_t)L_IMG * N_QKV;
  unsigned short* qa = (unsigned short*)(wsb + 57573376);
  unsigned short* ka = (unsigned short*)(wsb + 65437696);
  unsigned short* va = (unsigned short*)(wsb + 73302016); // ends 81,166,336
  unsigned short* attn = xm_img;                        // reuse (xm dead)
  float* img2 = (float*)(wsb + 10387456);               // reuse (qkv dead)
  float* txt2 = img2 + (size_t)L_IMG * D_MODEL;
  unsigned short* xm2_img = qa;                         // reuse (qa dead)
  unsigned short* xm2_txt = xm2_img + (size_t)L_IMG * D_MODEL;
  unsigned short* h_img = (unsigned short*)(wsb + 10387456 + 15728640);
  unsigned short* h_txt = h_img + (size_t)L_IMG * N_MLP;
  float* out_img = (float*)d_out;
  float* out_txt = out_img + (size_t)L_IMG * D_MODEL;
  float* mod_img = modv;
  float* mod_txt = modv + MOD_N;

  silu_kernel<<<12, 256, 0, stream>>>(vec, silu_s);
  mod_gemv_partial<<<dim3(72, 16, 2), 256, 0, stream>>>(silu_s, img_mod_w, txt_mod_w, part);
  mod_reduce<<<144, 256, 0, stream>>>(part, img_mod_b, txt_mod_b, modv);
  ln_mod_kernel<<<L_IMG, 256, 0, stream>>>(img, xm_img, mod_img, 0, 3072);
  ln_mod_kernel<<<L_TXT, 256, 0, stream>>>(txt, xm_txt, mod_txt, 0, 3072);

  // qkv: img tiles 72*8=576, txt tiles 72*2=144 -> 720 blocks
  gemm2_kernel<0><<<720, 256, 0, stream>>>(
      xm_img, img_qkv_w, img_qkv_b, qkv_img, nullptr, nullptr, nullptr,
      xm_txt, txt_qkv_w, txt_qkv_b, qkv_txt, nullptr, nullptr, nullptr,
      576, N_QKV, D_MODEL);

  rms_rope_kernel<<<dim3(L_ALL / 4, N_HEADS), 256, 0, stream>>>(qkv_img, qkv_txt, img_qnorm, img_knorm, txt_qnorm, txt_knorm, pe, qa, ka, va);
  attn_kernel<<<dim3(L_ALL / 64, N_HEADS), 256, 0, stream>>>(qa, ka, va, attn);

  // proj: img 24*8=192, txt 24*2=48 -> 240 blocks
  gemm2_kernel<2><<<240, 256, 0, stream>>>(
      attn + (size_t)L_TXT * D_MODEL, img_proj_w, img_proj_b, img2, nullptr, img, mod_img + 6144,
      attn, txt_proj_w, txt_proj_b, txt2, nullptr, txt, mod_txt + 6144,
      192, D_MODEL, D_MODEL);

  ln_mod_kernel<<<L_IMG, 256, 0, stream>>>(img2, xm2_img, mod_img, 9216, 12288);
  ln_mod_kernel<<<L_TXT, 256, 0, stream>>>(txt2, xm2_txt, mod_txt, 9216, 12288);

  // mlp1: img 96*8=768, txt 96*2=192 -> 960 blocks
  gemm2_kernel<1><<<960, 256, 0, stream>>>(
      xm2_img, img_mlp_w1, img_mlp_b1, nullptr, h_img, nullptr, nullptr,
      xm2_txt, txt_mlp_w1, txt_mlp_b1, nullptr, h_txt, nullptr, nullptr,
      768, N_MLP, D_MODEL);

  // mlp2: img 24*8=192, txt 24*2=48 -> 240 blocks
  gemm2_kernel<2><<<240, 256, 0, stream>>>(
      h_img, img_mlp_w2, img_mlp_b2, out_img, nullptr, img2, mod_img + 15360,
      h_txt, txt_mlp_w2, txt_mlp_b2, out_txt, nullptr, txt2, mod_txt + 15360,
      192, D_MODEL, N_MLP);
}